// Round 12
// baseline (529.077 us; speedup 1.0000x reference)
//
#include <hip/hip_runtime.h>

// Chamfer loss via MFMA, B=16, N=4096, D=3, fp32 in/out. Single dispatch.
// d2[p][q] = ||p||^2 + ||q||^2 - 2 p.q as one 32x32x16 f16 MFMA per tile,
// hi/lo f16 split (error ~1e-3; ||q||^2 added per-column after the min).
// Each block owns 256 output cols x ALL 4096 rows -> complete min -> plain
// stores (no atomics, no output init). Rows staged in 8 double-buffered
// 512-row LDS chunks. Inner loop is a 2-deep software pipeline: MFMA(t+1)
// issues BEFORE the min-trees of tile t, hiding MFMA-result latency behind
// VALU work. All register arrays statically indexed (r11 lesson: 16-tile
// register cache spills to scratch at 648 MB/dispatch).

typedef _Float16 half8    __attribute__((ext_vector_type(8)));
typedef float    floatx16 __attribute__((ext_vector_type(16)));

#define CH_B 16
#define CH_N 4096
#define CH_BLOCK 256
#define CH_COLS 256                    // output cols per block (64/wave)
#define CH_NCT (CH_N / CH_COLS)        // 16 col-tiles per (dir,b)
#define CH_CHUNK 512                   // staged rows per chunk
#define CH_NCHUNK (CH_N / CH_CHUNK)    // 8
#define CH_CT (CH_CHUNK / 32)          // 16 row-tiles per chunk
#define CH_NBLK (2 * CH_B * CH_NCT)    // 512 blocks (2 per CU)

__global__ __launch_bounds__(CH_BLOCK, 2) void chamfer_one(
    const float* __restrict__ src, const float* __restrict__ trg,
    float* __restrict__ out_all)
{
    __shared__ half8 sp[2][CH_CT * 64];   // 2 x 16 KB A-fragment buffers

    const int tid  = threadIdx.x;
    const int lane = tid & 63;
    const int wave = tid >> 6;
    const int l31  = lane & 31;
    const int lhi  = lane >> 5;

    const int L   = blockIdx.x;        // 0..511
    const int ct  = L & (CH_NCT - 1);  // col-tile
    const int bz  = L >> 4;            // dir*16 + b
    const int b   = bz & (CH_B - 1);
    const int dir = bz >> 4;

    const float* P  = dir ? trg : src;
    const float* Q  = dir ? src : trg;
    const float* Pb = P + (size_t)b * CH_N * 3;
    const float* Qb = Q + (size_t)b * CH_N * 3;
    float* out = out_all + ((size_t)dir * CH_B + b) * CH_N;

    // ---- B fragments: 2 sets of 32 cols (64 cols per wave) ----
    half8 bfrag[2];
    float qn[2], m[2];
    const int col0 = ct * CH_COLS + wave * 64 + l31;
    #pragma unroll
    for (int s = 0; s < 2; ++s) {
        const int col = col0 + s * 32;
        const float qx = Qb[col * 3 + 0], qy = Qb[col * 3 + 1], qz = Qb[col * 3 + 2];
        qn[s] = qx * qx + qy * qy + qz * qz;
        m[s]  = __builtin_inff();
        const _Float16 xh = (_Float16)qx, yh = (_Float16)qy, zh = (_Float16)qz;
        const _Float16 xl = (_Float16)(qx - (float)xh);
        const _Float16 yl = (_Float16)(qy - (float)yh);
        const _Float16 zl = (_Float16)(qz - (float)zh);
        half8 f;
        if (lhi == 0) {      // k = 0..7
            f[0] = (_Float16)1.0f; f[1] = (_Float16)1.0f;
            f[2] = xh; f[3] = yh; f[4] = zh;
            f[5] = xh; f[6] = yh; f[7] = zh;
        } else {             // k = 8..15
            f[0] = xl; f[1] = yl; f[2] = zl;
            f[3] = (_Float16)0.0f; f[4] = (_Float16)0.0f;
            f[5] = (_Float16)0.0f; f[6] = (_Float16)0.0f; f[7] = (_Float16)0.0f;
        }
        bfrag[s] = f;
    }

    // ---- staging: 2 rows per thread per chunk (scalar loads) ----
    const int r0 = (tid >> 5) * 64 + (tid & 31);   // rows 0..511
    const int r1 = r0 + 32;

    float pa[3], pb[3];
    auto loadpts = [&](int c) {
        const float* base = Pb + (size_t)c * CH_CHUNK * 3;
        pa[0] = base[r0 * 3 + 0];
        pa[1] = base[r0 * 3 + 1];
        pa[2] = base[r0 * 3 + 2];
        pb[0] = base[r1 * 3 + 0];
        pb[1] = base[r1 * 3 + 1];
        pb[2] = base[r1 * 3 + 2];
    };
    auto writept = [&](int buf, int r, float px, float py, float pz) {
        const float ax = -2.0f * px, ay = -2.0f * py, az = -2.0f * pz;
        const float pn = px * px + py * py + pz * pz;
        const _Float16 axh = (_Float16)ax, ayh = (_Float16)ay, azh = (_Float16)az;
        const _Float16 axl = (_Float16)(ax - (float)axh);
        const _Float16 ayl = (_Float16)(ay - (float)ayh);
        const _Float16 azl = (_Float16)(az - (float)azh);
        const _Float16 pnh = (_Float16)pn, pnl = (_Float16)(pn - (float)pnh);
        const _Float16 z0 = (_Float16)0.0f;
        const half8 k0 = {pnh, pnl, axh, ayh, azh, axl, ayl, azl};  // k 0..7
        const half8 k1 = {axh, ayh, azh, z0, z0, z0, z0, z0};       // k 8..15
        sp[buf][(r >> 5) * 64 + (r & 31)]      = k0;
        sp[buf][(r >> 5) * 64 + 32 + (r & 31)] = k1;
    };

    // prologue: stage chunk 0
    loadpts(0);
    writept(0, r0, pa[0], pa[1], pa[2]);
    writept(0, r1, pb[0], pb[1], pb[2]);
    __syncthreads();

    const floatx16 zero = {0.f,0.f,0.f,0.f,0.f,0.f,0.f,0.f,
                           0.f,0.f,0.f,0.f,0.f,0.f,0.f,0.f};

    #pragma unroll 1
    for (int c = 0; c < CH_NCHUNK; ++c) {
        const int cur = c & 1;
        const bool more = (c + 1 < CH_NCHUNK);
        if (more) loadpts(c + 1);   // issue early; consumed after compute

        const half8* buf = sp[cur];

        // ---- 2-deep pipeline: MFMA(t+1) issues before trees of tile t ----
        half8 a_cur = buf[lane];            // tile 0
        half8 a_nxt = buf[64 + lane];       // tile 1
        floatx16 e0 = __builtin_amdgcn_mfma_f32_32x32x16_f16(a_cur, bfrag[0], zero, 0, 0, 0);
        floatx16 e1 = __builtin_amdgcn_mfma_f32_32x32x16_f16(a_cur, bfrag[1], zero, 0, 0, 0);

        #pragma unroll
        for (int t = 0; t < CH_CT; ++t) {
            floatx16 f0, f1;
            if (t + 1 < CH_CT) {   // issue next tile's MFMAs first
                f0 = __builtin_amdgcn_mfma_f32_32x32x16_f16(a_nxt, bfrag[0], zero, 0, 0, 0);
                f1 = __builtin_amdgcn_mfma_f32_32x32x16_f16(a_nxt, bfrag[1], zero, 0, 0, 0);
            }
            half8 a_pf = a_nxt;
            if (t + 2 < CH_CT) a_pf = buf[(t + 2) * 64 + lane];
            // trees of tile t run while tile t+1's MFMAs are in the pipe
            {
                const float u0 = fminf(fminf(e0[0],  e0[1]),  e0[2]);
                const float u1 = fminf(fminf(e0[3],  e0[4]),  e0[5]);
                const float u2 = fminf(fminf(e0[6],  e0[7]),  e0[8]);
                const float u3 = fminf(fminf(e0[9],  e0[10]), e0[11]);
                const float u4 = fminf(fminf(e0[12], e0[13]), e0[14]);
                const float v  = fminf(fminf(u0, u1), u2);
                const float w  = fminf(fminf(u3, u4), e0[15]);
                m[0] = fminf(fminf(m[0], v), w);
            }
            {
                const float u0 = fminf(fminf(e1[0],  e1[1]),  e1[2]);
                const float u1 = fminf(fminf(e1[3],  e1[4]),  e1[5]);
                const float u2 = fminf(fminf(e1[6],  e1[7]),  e1[8]);
                const float u3 = fminf(fminf(e1[9],  e1[10]), e1[11]);
                const float u4 = fminf(fminf(e1[12], e1[13]), e1[14]);
                const float v  = fminf(fminf(u0, u1), u2);
                const float w  = fminf(fminf(u3, u4), e1[15]);
                m[1] = fminf(fminf(m[1], v), w);
            }
            if (t + 1 < CH_CT) { e0 = f0; e1 = f1; }
            a_nxt = a_pf;
        }

        if (more) {   // LDS writes late: global-load latency hidden by compute
            writept(cur ^ 1, r0, pa[0], pa[1], pa[2]);
            writept(cur ^ 1, r1, pb[0], pb[1], pb[2]);
        }
        __syncthreads();
    }

    // ---- epilogue: add ||q||^2, clamp >=0, fold row-halves, plain store ----
    #pragma unroll
    for (int s = 0; s < 2; ++s) {
        float v = fmaxf(m[s] + qn[s], 0.0f);
        v = fminf(v, __shfl_xor(v, 32));
        if (lane < 32) out[col0 + s * 32] = v;
    }
}

extern "C" void kernel_launch(void* const* d_in, const int* in_sizes, int n_in,
                              void* d_out, int out_size, void* d_ws, size_t ws_size,
                              hipStream_t stream) {
    const float* src = (const float*)d_in[0];
    const float* trg = (const float*)d_in[1];
    float* out = (float*)d_out;

    chamfer_one<<<dim3(CH_NBLK), dim3(CH_BLOCK), 0, stream>>>(src, trg, out);
}

// Round 13
// 23.631 us; speedup vs baseline: 22.3889x; 22.3889x over previous
//
#include <hip/hip_runtime.h>

// Chamfer loss via MFMA, B=16, N=4096, D=3, fp32 in/out. Single dispatch.
// d2[p][q] = ||p||^2 + ||q||^2 - 2 p.q as one 32x32x16 f16 MFMA per tile,
// hi/lo f16 split (error ~1e-3; ||q||^2 added per-column after the min).
// 1024-thread blocks (16 waves = 4 waves/SIMD for latency hiding), 1 block/CU.
// Each block: 512 output cols x ALL 4096 rows -> complete min -> plain stores
// (no atomics, no init). Each wave: 32 cols (1 bfrag, 1 accumulator -> low
// VGPR, no spill; r11/r12 lesson). Rows staged in 4 double-buffered 1024-row
// LDS chunks (64 KB); rolling 1-deep a-tile prefetch, unroll 4 (r9's stable
// codegen point). Per-wave tile-phase stagger decorrelates MFMA bursts.

typedef _Float16 half8    __attribute__((ext_vector_type(8)));
typedef float    floatx16 __attribute__((ext_vector_type(16)));

#define CH_B 16
#define CH_N 4096
#define CH_BLOCK 1024                  // 16 waves
#define CH_COLS 512                    // output cols per block (32/wave)
#define CH_NCT (CH_N / CH_COLS)        // 8 col-tiles per (dir,b)
#define CH_CHUNK 1024                  // staged rows per chunk
#define CH_NCHUNK (CH_N / CH_CHUNK)    // 4
#define CH_CT (CH_CHUNK / 32)          // 32 row-tiles per chunk
#define CH_NBLK (2 * CH_B * CH_NCT)    // 256 blocks (1 per CU)

__global__ __launch_bounds__(CH_BLOCK, 4) void chamfer_one(
    const float* __restrict__ src, const float* __restrict__ trg,
    float* __restrict__ out_all)
{
    __shared__ half8 sp[2][CH_CT * 64];   // 2 x 32 KB A-fragment buffers

    const int tid  = threadIdx.x;
    const int lane = tid & 63;
    const int wave = tid >> 6;            // 0..15
    const int l31  = lane & 31;
    const int lhi  = lane >> 5;

    const int L   = blockIdx.x;           // 0..255
    const int ct  = L & (CH_NCT - 1);     // col-tile
    const int bz  = L >> 3;               // dir*16 + b
    const int b   = bz & (CH_B - 1);
    const int dir = bz >> 4;

    const float* P  = dir ? trg : src;
    const float* Q  = dir ? src : trg;
    const float* Pb = P + (size_t)b * CH_N * 3;
    const float* Qb = Q + (size_t)b * CH_N * 3;
    float* out = out_all + ((size_t)dir * CH_B + b) * CH_N;

    // ---- B fragment: 32 cols per wave ----
    const int col0 = ct * CH_COLS + wave * 32 + l31;
    float qn, m = __builtin_inff();
    half8 bfrag;
    {
        const float qx = Qb[col0 * 3 + 0], qy = Qb[col0 * 3 + 1], qz = Qb[col0 * 3 + 2];
        qn = qx * qx + qy * qy + qz * qz;
        const _Float16 xh = (_Float16)qx, yh = (_Float16)qy, zh = (_Float16)qz;
        const _Float16 xl = (_Float16)(qx - (float)xh);
        const _Float16 yl = (_Float16)(qy - (float)yh);
        const _Float16 zl = (_Float16)(qz - (float)zh);
        half8 f;
        if (lhi == 0) {      // k = 0..7
            f[0] = (_Float16)1.0f; f[1] = (_Float16)1.0f;
            f[2] = xh; f[3] = yh; f[4] = zh;
            f[5] = xh; f[6] = yh; f[7] = zh;
        } else {             // k = 8..15
            f[0] = xl; f[1] = yl; f[2] = zl;
            f[3] = (_Float16)0.0f; f[4] = (_Float16)0.0f;
            f[5] = (_Float16)0.0f; f[6] = (_Float16)0.0f; f[7] = (_Float16)0.0f;
        }
        bfrag = f;
    }

    // ---- staging: 1 row per thread per chunk (scalar loads) ----
    float pa[3];
    auto loadpts = [&](int c) {
        const float* base = Pb + ((size_t)c * CH_CHUNK + tid) * 3;
        pa[0] = base[0];
        pa[1] = base[1];
        pa[2] = base[2];
    };
    auto writept = [&](int buf) {
        const float ax = -2.0f * pa[0], ay = -2.0f * pa[1], az = -2.0f * pa[2];
        const float pn = pa[0] * pa[0] + pa[1] * pa[1] + pa[2] * pa[2];
        const _Float16 axh = (_Float16)ax, ayh = (_Float16)ay, azh = (_Float16)az;
        const _Float16 axl = (_Float16)(ax - (float)axh);
        const _Float16 ayl = (_Float16)(ay - (float)ayh);
        const _Float16 azl = (_Float16)(az - (float)azh);
        const _Float16 pnh = (_Float16)pn, pnl = (_Float16)(pn - (float)pnh);
        const _Float16 z0 = (_Float16)0.0f;
        const half8 k0 = {pnh, pnl, axh, ayh, azh, axl, ayl, azl};  // k 0..7
        const half8 k1 = {axh, ayh, azh, z0, z0, z0, z0, z0};       // k 8..15
        sp[buf][(tid >> 5) * 64 + (tid & 31)]      = k0;
        sp[buf][(tid >> 5) * 64 + 32 + (tid & 31)] = k1;
    };

    // prologue: stage chunk 0
    loadpts(0);
    writept(0);
    __syncthreads();

    const floatx16 zero = {0.f,0.f,0.f,0.f,0.f,0.f,0.f,0.f,
                           0.f,0.f,0.f,0.f,0.f,0.f,0.f,0.f};
    const int off = wave * 2;   // per-wave tile-phase stagger (0..30)

    #pragma unroll 1
    for (int c = 0; c < CH_NCHUNK; ++c) {
        const int cur = c & 1;
        const bool more = (c + 1 < CH_NCHUNK);
        if (more) loadpts(c + 1);   // issue early; consumed after compute

        const half8* buf = sp[cur];
        half8 a0 = buf[(off & (CH_CT - 1)) * 64 + lane];
        #pragma unroll 4
        for (int t = 0; t < CH_CT; ++t) {
            half8 a1 = a0;
            if (t + 1 < CH_CT) a1 = buf[((t + 1 + off) & (CH_CT - 1)) * 64 + lane];
            const floatx16 d =
                __builtin_amdgcn_mfma_f32_32x32x16_f16(a0, bfrag, zero, 0, 0, 0);
            {   // min3-shaped reduction: ~9 instrs per 16 values
                const float u0 = fminf(fminf(d[0],  d[1]),  d[2]);
                const float u1 = fminf(fminf(d[3],  d[4]),  d[5]);
                const float u2 = fminf(fminf(d[6],  d[7]),  d[8]);
                const float u3 = fminf(fminf(d[9],  d[10]), d[11]);
                const float u4 = fminf(fminf(d[12], d[13]), d[14]);
                const float v  = fminf(fminf(u0, u1), u2);
                const float w  = fminf(fminf(u3, u4), d[15]);
                m = fminf(fminf(m, v), w);
            }
            a0 = a1;
        }

        if (more) writept(cur ^ 1);   // LDS writes late (load latency hidden)
        __syncthreads();
    }

    // ---- epilogue: add ||q||^2, clamp >=0, fold row-halves, plain store ----
    float v = fmaxf(m + qn, 0.0f);
    v = fminf(v, __shfl_xor(v, 32));
    if (lane < 32) out[col0] = v;
}

extern "C" void kernel_launch(void* const* d_in, const int* in_sizes, int n_in,
                              void* d_out, int out_size, void* d_ws, size_t ws_size,
                              hipStream_t stream) {
    const float* src = (const float*)d_in[0];
    const float* trg = (const float*)d_in[1];
    float* out = (float*)d_out;

    chamfer_one<<<dim3(CH_NBLK), dim3(CH_BLOCK), 0, stream>>>(src, trg, out);
}